// Round 1
// baseline (76.630 us; speedup 1.0000x reference)
//
#include <hip/hip_runtime.h>
#include <math.h>

#define BB 8
#define HH 256
#define WW 256

// ---------------------------------------------------------------------------
// Kernel 1: vertical 1D distance scans (exact reference semantics).
// One thread per column (b, j). Forward scan writes raw distance; backward
// scan takes min, squares, writes g^2 for both mask (g2o) and ~mask (g2i).
// Distances are exact small integers representable in f32.
// ---------------------------------------------------------------------------
__global__ void edt_vertical_kernel(const int* __restrict__ targets,
                                    float* __restrict__ g2o,
                                    float* __restrict__ g2i,
                                    int* __restrict__ flags) {
    const int b = blockIdx.x;          // 0..BB-1
    const int j = threadIdx.x;         // 0..WW-1
    const int* t = targets + (size_t)b * HH * WW;
    float* go = g2o + (size_t)b * HH * WW;
    float* gi = g2i + (size_t)b * HH * WW;
    const float BIG = (float)(HH + WW);   // matches reference BIG = h + w

    float co = BIG, ci = BIG;
    bool any = false;
    #pragma unroll 4
    for (int i = 0; i < HH; ++i) {
        const bool m = (t[i * WW + j] != 0);
        any |= m;
        co = m ? 0.0f : co + 1.0f;   // dist to nearest mask-True above
        ci = m ? ci + 1.0f : 0.0f;   // dist to nearest mask-False above
        go[i * WW + j] = co;
        gi[i * WW + j] = ci;
    }
    co = BIG; ci = BIG;
    #pragma unroll 4
    for (int i = HH - 1; i >= 0; --i) {
        const bool m = (t[i * WW + j] != 0);
        co = m ? 0.0f : co + 1.0f;
        ci = m ? ci + 1.0f : 0.0f;
        const float vo = fminf(go[i * WW + j], co);
        const float vi = fminf(gi[i * WW + j], ci);
        go[i * WW + j] = vo * vo;    // store g^2 (exact integer in f32)
        gi[i * WW + j] = vi * vi;
    }
    if (any) flags[b] = 1;           // benign same-value race; flags pre-zeroed
}

// ---------------------------------------------------------------------------
// Kernel 2: per-row min-plus combine + fused loss contribution + reduction.
// One block per row (b, i), 256 threads (one per output column j).
// d2[j] = min_l (g2[l] + (j-l)^2)  -- exact integer math in f32.
// contribution = sigmoid(logit) * (sqrt(d2_out) - sqrt(d2_in)) in f64.
// ---------------------------------------------------------------------------
__global__ void combine_reduce_kernel(const float* __restrict__ logits,
                                      const float* __restrict__ g2o,
                                      const float* __restrict__ g2i,
                                      double* __restrict__ batchsum) {
    const int row = blockIdx.x;        // b*HH + i
    const int b = row / HH;
    const int j = threadIdx.x;

    __shared__ __align__(16) float so[WW];
    __shared__ __align__(16) float si[WW];
    __shared__ double wsum[4];

    so[j] = g2o[(size_t)row * WW + j];
    si[j] = g2i[(size_t)row * WW + j];
    __syncthreads();

    float d2o = 1e30f, d2i = 1e30f;
    float df = (float)j;               // (j - l) for current l, decremented
    #pragma unroll 4
    for (int l = 0; l < WW; l += 4) {
        const float4 o4 = *reinterpret_cast<const float4*>(&so[l]);  // broadcast
        const float4 i4 = *reinterpret_cast<const float4*>(&si[l]);
        float sq;
        sq = df * df; d2o = fminf(d2o, o4.x + sq); d2i = fminf(d2i, i4.x + sq); df -= 1.0f;
        sq = df * df; d2o = fminf(d2o, o4.y + sq); d2i = fminf(d2i, i4.y + sq); df -= 1.0f;
        sq = df * df; d2o = fminf(d2o, o4.z + sq); d2i = fminf(d2i, i4.z + sq); df -= 1.0f;
        sq = df * df; d2o = fminf(d2o, o4.w + sq); d2i = fminf(d2i, i4.w + sq); df -= 1.0f;
    }

    const double sdf = sqrt((double)d2o) - sqrt((double)d2i);
    const double x  = (double)logits[(size_t)row * WW + j];
    const double p  = 1.0 / (1.0 + exp(-x));
    double c = p * sdf;

    // wave-64 shuffle reduce, then cross-wave via LDS
    #pragma unroll
    for (int off = 32; off > 0; off >>= 1)
        c += __shfl_down(c, off, 64);
    const int lane = threadIdx.x & 63;
    const int wid  = threadIdx.x >> 6;
    if (lane == 0) wsum[wid] = c;
    __syncthreads();
    if (threadIdx.x == 0)
        atomicAdd(&batchsum[b], wsum[0] + wsum[1] + wsum[2] + wsum[3]);
}

// ---------------------------------------------------------------------------
// Kernel 3: finalize. loss = sum_b (flag ? s_b : 0) / (B*H*W).
// (mean over pixels then mean over batch == global sum / (B*H*W))
// ---------------------------------------------------------------------------
__global__ void finalize_kernel(const double* __restrict__ batchsum,
                                const int* __restrict__ flags,
                                float* __restrict__ out) {
    if (threadIdx.x == 0 && blockIdx.x == 0) {
        double total = 0.0;
        for (int b = 0; b < BB; ++b)
            if (flags[b]) total += batchsum[b];
        out[0] = (float)(total / (double)((long long)BB * HH * WW));
    }
}

extern "C" void kernel_launch(void* const* d_in, const int* in_sizes, int n_in,
                              void* d_out, int out_size, void* d_ws, size_t ws_size,
                              hipStream_t stream) {
    const float* logits  = (const float*)d_in[0];
    const int*   targets = (const int*)d_in[1];
    float*       out     = (float*)d_out;

    char* ws = (char*)d_ws;
    const size_t n_img   = (size_t)BB * HH * WW;       // 524288
    const size_t off_g2o = 0;
    const size_t off_g2i = n_img * sizeof(float);      // 2 MB
    const size_t off_sum = off_g2i * 2;                // 4 MB (8-byte aligned)
    const size_t off_flg = off_sum + BB * sizeof(double);

    float*  g2o      = (float*)(ws + off_g2o);
    float*  g2i      = (float*)(ws + off_g2i);
    double* batchsum = (double*)(ws + off_sum);
    int*    flags    = (int*)(ws + off_flg);

    // zero accumulators + flags every call (harness does not re-poison)
    hipMemsetAsync(ws + off_sum, 0, BB * sizeof(double) + BB * sizeof(int), stream);

    edt_vertical_kernel<<<BB, WW, 0, stream>>>(targets, g2o, g2i, flags);
    combine_reduce_kernel<<<BB * HH, WW, 0, stream>>>(logits, g2o, g2i, batchsum);
    finalize_kernel<<<1, 64, 0, stream>>>(batchsum, flags, out);
}

// Round 2
// 44.160 us; speedup vs baseline: 1.7353x; 1.7353x over previous
//
#include <hip/hip_runtime.h>
#include <math.h>

#define BB 8
#define HH 256
#define WW 256

// ---------------------------------------------------------------------------
// Kernel A: build per-column 256-bit occupancy masks (4 x u64 per column) and
// per-batch any() flags. Grid (BB, 4): block (b, word w) covers rows
// 64w..64w+63; 256 threads, one per column j. Reads are fully coalesced.
// ---------------------------------------------------------------------------
__global__ void build_colbits_kernel(const int* __restrict__ targets,
                                     unsigned long long* __restrict__ colbits,
                                     int* __restrict__ flags) {
    const int b = blockIdx.x;
    const int w = blockIdx.y;          // 0..3
    const int j = threadIdx.x;         // 0..255
    const int* t = targets + ((size_t)b * HH + 64 * w) * WW + j;
    unsigned long long bits = 0ull;
    #pragma unroll
    for (int r = 0; r < 64; ++r)
        bits |= (unsigned long long)(t[r * WW] != 0) << r;
    colbits[((size_t)(b * WW + j) << 2) + w] = bits;
    if (bits) flags[b] = 1;            // benign same-value race; pre-zeroed
}

// ---------------------------------------------------------------------------
// Vertical 1D distance from the 256-bit column mask, matching the reference
// scan semantics exactly:
//   d(i) = min( i - prev_set(i), next_set(i) - i, i + 513, 768 - i )
// The last two terms are the BIG=h+w=512 sentinels of the sequential scans
// (no True above -> 513+i; no True below -> 513+(255-i)). All values are
// small exact integers.  `i` is block-uniform -> shifts become SALU; word
// index k is compile-time (no runtime-indexed arrays -> no scratch).
// ---------------------------------------------------------------------------
__device__ __forceinline__ float col_dist(unsigned long long w0, unsigned long long w1,
                                          unsigned long long w2, unsigned long long w3,
                                          int i) {
    const int INF = 1 << 20;
    int best = min(i + 513, 768 - i);
    const unsigned long long ws[4] = {w0, w1, w2, w3};
    #pragma unroll
    for (int k = 0; k < 4; ++k) {
        const unsigned long long wk = ws[k];
        const int rel = i - 64 * k;            // position of i within word k
        // next set bit at row >= i
        {
            const int sh = min(max(rel, 0), 63);
            const unsigned long long m = (rel < 64) ? (wk >> sh) : 0ull;
            const int d = m ? (__ffsll((unsigned long long)m) - 1 + sh - rel) : INF;
            best = min(best, d);
        }
        // prev set bit at row <= i
        {
            const int sh = min(max(63 - rel, 0), 63);
            const unsigned long long m = (rel >= 0) ? (wk << sh) : 0ull;
            const int add = rel > 63 ? rel - 63 : 0;
            const int d = m ? (__clzll((long long)m) + add) : INF;
            best = min(best, d);
        }
    }
    return (float)best;
}

// ---------------------------------------------------------------------------
// Kernel B: one block per row (b, i), 256 threads (one per column j).
// Reconstruct g^2 for mask and ~mask from column bitmasks (registers), stage
// the row in LDS, exact min-plus combine, fused sigmoid*sdf, f64 reduction.
// ---------------------------------------------------------------------------
__global__ void fused_row_kernel(const float* __restrict__ logits,
                                 const unsigned long long* __restrict__ colbits,
                                 double* __restrict__ batchsum) {
    const int row = blockIdx.x;        // b*HH + i
    const int b = row >> 8;
    const int i = row & 255;
    const int j = threadIdx.x;

    __shared__ __align__(16) float so[WW];
    __shared__ __align__(16) float si[WW];
    __shared__ double wsum[4];

    const unsigned long long* cb = colbits + ((size_t)(b * WW + j) << 2);
    const unsigned long long w0 = cb[0], w1 = cb[1], w2 = cb[2], w3 = cb[3];
    const float x = logits[(size_t)row * WW + j];   // issue early

    const float go = col_dist(w0, w1, w2, w3, i);
    const float gi = col_dist(~w0, ~w1, ~w2, ~w3, i);
    so[j] = go * go;                   // exact integers (<= 768^2) in f32
    si[j] = gi * gi;
    __syncthreads();

    float d2o = 1e30f, d2i = 1e30f;
    float df = (float)j;               // (j - l), decremented per l
    #pragma unroll 4
    for (int l = 0; l < WW; l += 4) {
        const float4 o4 = *reinterpret_cast<const float4*>(&so[l]);  // broadcast
        const float4 i4 = *reinterpret_cast<const float4*>(&si[l]);
        float sq;
        sq = df * df; d2o = fminf(d2o, o4.x + sq); d2i = fminf(d2i, i4.x + sq); df -= 1.0f;
        sq = df * df; d2o = fminf(d2o, o4.y + sq); d2i = fminf(d2i, i4.y + sq); df -= 1.0f;
        sq = df * df; d2o = fminf(d2o, o4.z + sq); d2i = fminf(d2i, i4.z + sq); df -= 1.0f;
        sq = df * df; d2o = fminf(d2o, o4.w + sq); d2i = fminf(d2i, i4.w + sq); df -= 1.0f;
    }

    const double sdf = sqrt((double)d2o) - sqrt((double)d2i);
    const double p  = 1.0 / (1.0 + exp(-(double)x));
    double c = p * sdf;

    #pragma unroll
    for (int off = 32; off > 0; off >>= 1)
        c += __shfl_down(c, off, 64);
    const int lane = threadIdx.x & 63;
    const int wid  = threadIdx.x >> 6;
    if (lane == 0) wsum[wid] = c;
    __syncthreads();
    if (threadIdx.x == 0)
        atomicAdd(&batchsum[b], wsum[0] + wsum[1] + wsum[2] + wsum[3]);
}

// ---------------------------------------------------------------------------
// Kernel C: finalize. loss = sum_b (flag ? s_b : 0) / (B*H*W).
// ---------------------------------------------------------------------------
__global__ void finalize_kernel(const double* __restrict__ batchsum,
                                const int* __restrict__ flags,
                                float* __restrict__ out) {
    if (threadIdx.x == 0 && blockIdx.x == 0) {
        double total = 0.0;
        for (int b = 0; b < BB; ++b)
            if (flags[b]) total += batchsum[b];
        out[0] = (float)(total / (double)((long long)BB * HH * WW));
    }
}

extern "C" void kernel_launch(void* const* d_in, const int* in_sizes, int n_in,
                              void* d_out, int out_size, void* d_ws, size_t ws_size,
                              hipStream_t stream) {
    const float* logits  = (const float*)d_in[0];
    const int*   targets = (const int*)d_in[1];
    float*       out     = (float*)d_out;

    char* ws = (char*)d_ws;
    const size_t off_bits = 0;                                        // 64 KB
    const size_t off_sum  = (size_t)BB * WW * 4 * sizeof(unsigned long long);
    const size_t off_flg  = off_sum + BB * sizeof(double);

    unsigned long long* colbits = (unsigned long long*)(ws + off_bits);
    double* batchsum = (double*)(ws + off_sum);
    int*    flags    = (int*)(ws + off_flg);

    hipMemsetAsync(ws + off_sum, 0, BB * sizeof(double) + BB * sizeof(int), stream);

    build_colbits_kernel<<<dim3(BB, 4), WW, 0, stream>>>(targets, colbits, flags);
    fused_row_kernel<<<BB * HH, WW, 0, stream>>>(logits, colbits, batchsum);
    finalize_kernel<<<1, 64, 0, stream>>>(batchsum, flags, out);
}

// Round 3
// 26.422 us; speedup vs baseline: 2.9003x; 1.6713x over previous
//
#include <hip/hip_runtime.h>
#include <math.h>

#define BB 8
#define HH 256
#define WW 256

// Workspace layout (all slots written unconditionally every call -> no
// pre-zeroing, no memset node in the graph):
//   colbits : BB*WW*4 u64  = 65536 B
//   blockany: BB*4   int   =   128 B
//   partial : BB*HH  double= 16384 B

// ---------------------------------------------------------------------------
// Kernel A: build per-column 256-bit occupancy masks (4 x u64 per column) and
// per-(b,word) any-flags. Grid (BB, 4): block (b, w) covers rows 64w..64w+63;
// 256 threads, one per column j. Row reads are fully coalesced.
// ---------------------------------------------------------------------------
__global__ void build_colbits_kernel(const int* __restrict__ targets,
                                     unsigned long long* __restrict__ colbits,
                                     int* __restrict__ blockany) {
    const int b = blockIdx.x;
    const int w = blockIdx.y;          // 0..3
    const int j = threadIdx.x;         // 0..255
    const int* t = targets + ((size_t)b * HH + 64 * w) * WW + j;
    unsigned long long bits = 0ull;
    #pragma unroll
    for (int r = 0; r < 64; ++r)
        bits |= (unsigned long long)(t[r * WW] != 0) << r;
    colbits[((size_t)(b * WW + j) << 2) + w] = bits;

    __shared__ int anyw[4];
    const unsigned long long ba = __ballot(bits != 0ull);
    if ((j & 63) == 0) anyw[j >> 6] = (ba != 0ull) ? 1 : 0;
    __syncthreads();
    if (j == 0)
        blockany[b * 4 + w] = anyw[0] | anyw[1] | anyw[2] | anyw[3];
}

// ---------------------------------------------------------------------------
// Vertical 1D distance from the 256-bit column mask, matching the reference
// scan semantics exactly:
//   d(i) = min( i - prev_set(i), next_set(i) - i, i + 513, 768 - i )
// (BIG = h+w = 512 sentinels of the sequential scans.) Exact small integers.
// ---------------------------------------------------------------------------
__device__ __forceinline__ float col_dist(unsigned long long w0, unsigned long long w1,
                                          unsigned long long w2, unsigned long long w3,
                                          int i) {
    const int INF = 1 << 20;
    int best = min(i + 513, 768 - i);
    const unsigned long long ws[4] = {w0, w1, w2, w3};
    #pragma unroll
    for (int k = 0; k < 4; ++k) {
        const unsigned long long wk = ws[k];
        const int rel = i - 64 * k;            // position of i within word k
        // next set bit at row >= i
        {
            const int sh = min(max(rel, 0), 63);
            const unsigned long long m = (rel < 64) ? (wk >> sh) : 0ull;
            const int d = m ? (__ffsll((unsigned long long)m) - 1 + sh - rel) : INF;
            best = min(best, d);
        }
        // prev set bit at row <= i
        {
            const int sh = min(max(63 - rel, 0), 63);
            const unsigned long long m = (rel >= 0) ? (wk << sh) : 0ull;
            const int add = rel > 63 ? rel - 63 : 0;
            const int d = m ? (__clzll((long long)m) + add) : INF;
            best = min(best, d);
        }
    }
    return (float)best;
}

// ---------------------------------------------------------------------------
// Kernel B: one block per row (b, i), 256 threads (one per column j).
// Reconstruct g^2 from column bitmasks, stage row in LDS, exact min-plus
// combine (FMA form: fmaf(df,df,g2) is exact for integers < 2^24), fused
// sigmoid*sdf, f64 block reduce, unconditional per-block partial write.
// ---------------------------------------------------------------------------
__global__ void fused_row_kernel(const float* __restrict__ logits,
                                 const unsigned long long* __restrict__ colbits,
                                 double* __restrict__ partial) {
    const int row = blockIdx.x;        // b*HH + i
    const int b = row >> 8;
    const int i = row & 255;
    const int j = threadIdx.x;

    __shared__ __align__(16) float so[WW];
    __shared__ __align__(16) float si[WW];
    __shared__ double wsum[4];

    const unsigned long long* cb = colbits + ((size_t)(b * WW + j) << 2);
    const unsigned long long w0 = cb[0], w1 = cb[1], w2 = cb[2], w3 = cb[3];
    const float x = logits[(size_t)row * WW + j];   // issue early

    const float go = col_dist(w0, w1, w2, w3, i);
    const float gi = col_dist(~w0, ~w1, ~w2, ~w3, i);
    so[j] = go * go;                   // exact integers (<= 768^2) in f32
    si[j] = gi * gi;
    __syncthreads();

    float d2o = 1e30f, d2i = 1e30f;
    float df = (float)j;               // (j - l), decremented per l
    #pragma unroll 4
    for (int l = 0; l < WW; l += 4) {
        const float4 o4 = *reinterpret_cast<const float4*>(&so[l]);  // broadcast
        const float4 i4 = *reinterpret_cast<const float4*>(&si[l]);
        d2o = fminf(d2o, fmaf(df, df, o4.x)); d2i = fminf(d2i, fmaf(df, df, i4.x)); df -= 1.0f;
        d2o = fminf(d2o, fmaf(df, df, o4.y)); d2i = fminf(d2i, fmaf(df, df, i4.y)); df -= 1.0f;
        d2o = fminf(d2o, fmaf(df, df, o4.z)); d2i = fminf(d2i, fmaf(df, df, i4.z)); df -= 1.0f;
        d2o = fminf(d2o, fmaf(df, df, o4.w)); d2i = fminf(d2i, fmaf(df, df, i4.w)); df -= 1.0f;
    }

    const double sdf = sqrt((double)d2o) - sqrt((double)d2i);
    const double p  = 1.0 / (1.0 + exp(-(double)x));
    double c = p * sdf;

    #pragma unroll
    for (int off = 32; off > 0; off >>= 1)
        c += __shfl_down(c, off, 64);
    const int lane = threadIdx.x & 63;
    const int wid  = threadIdx.x >> 6;
    if (lane == 0) wsum[wid] = c;
    __syncthreads();
    if (threadIdx.x == 0)
        partial[row] = wsum[0] + wsum[1] + wsum[2] + wsum[3];   // no atomics
}

// ---------------------------------------------------------------------------
// Kernel C: finalize. 1 block x 256 threads; thread t sums partial[b*256+t]
// gated by batch-any flag; shuffle+LDS reduce; single write to out.
// ---------------------------------------------------------------------------
__global__ void finalize_kernel(const double* __restrict__ partial,
                                const int* __restrict__ blockany,
                                float* __restrict__ out) {
    const int t = threadIdx.x;         // 0..255
    double s = 0.0;
    #pragma unroll
    for (int b = 0; b < BB; ++b) {
        const int f = blockany[4*b] | blockany[4*b+1] | blockany[4*b+2] | blockany[4*b+3];
        const double v = partial[b * HH + t];
        s += f ? v : 0.0;
    }
    #pragma unroll
    for (int off = 32; off > 0; off >>= 1)
        s += __shfl_down(s, off, 64);
    __shared__ double wsum[4];
    if ((t & 63) == 0) wsum[t >> 6] = s;
    __syncthreads();
    if (t == 0)
        out[0] = (float)((wsum[0] + wsum[1] + wsum[2] + wsum[3])
                         / (double)((long long)BB * HH * WW));
}

extern "C" void kernel_launch(void* const* d_in, const int* in_sizes, int n_in,
                              void* d_out, int out_size, void* d_ws, size_t ws_size,
                              hipStream_t stream) {
    const float* logits  = (const float*)d_in[0];
    const int*   targets = (const int*)d_in[1];
    float*       out     = (float*)d_out;

    char* ws = (char*)d_ws;
    const size_t off_bits = 0;                                            // 64 KB
    const size_t off_any  = (size_t)BB * WW * 4 * sizeof(unsigned long long);
    const size_t off_par  = off_any + 128;                                // 8B-aligned

    unsigned long long* colbits  = (unsigned long long*)(ws + off_bits);
    int*                blockany = (int*)(ws + off_any);
    double*             partial  = (double*)(ws + off_par);

    build_colbits_kernel<<<dim3(BB, 4), WW, 0, stream>>>(targets, colbits, blockany);
    fused_row_kernel<<<BB * HH, WW, 0, stream>>>(logits, colbits, partial);
    finalize_kernel<<<1, WW, 0, stream>>>(partial, blockany, out);
}